// Round 1
// baseline (624.536 us; speedup 1.0000x reference)
//
#include <hip/hip_runtime.h>
#include <cstdint>
#include <cstddef>

// Raw bf16 bit-pattern fragments (guide §3: compile-verified short-based frags)
typedef __attribute__((ext_vector_type(8))) short bf16x8;
typedef __attribute__((ext_vector_type(4))) float f32x4;
typedef __attribute__((ext_vector_type(4))) unsigned short ushort4_;

#define MFMA16(a, b, c) __builtin_amdgcn_mfma_f32_16x16x32_bf16((a), (b), (c), 0, 0, 0)

__device__ __forceinline__ unsigned short f2bf(float f) {
  union { float f; unsigned u; } c; c.f = f;
  unsigned r = c.u + 0x7fffu + ((c.u >> 16) & 1u);
  return (unsigned short)(r >> 16);
}

// ---------------- fp32 -> bf16 ----------------
__global__ __launch_bounds__(256) void k_cvt(const float* __restrict__ x,
                                             unsigned short* __restrict__ y) {
  int i = blockIdx.x * 256 + threadIdx.x;  // exact grid: n/4 threads
  float4 v = reinterpret_cast<const float4*>(x)[i];
  ushort4_ o;
  o.x = f2bf(v.x); o.y = f2bf(v.y); o.z = f2bf(v.z); o.w = f2bf(v.w);
  reinterpret_cast<ushort4_*>(y)[i] = o;
}

// ---------------- W[K=2048][N] fp32 -> WT[N][2048] bf16 ----------------
__global__ __launch_bounds__(256) void k_transpose_cvt(const float* __restrict__ W,
                                                       unsigned short* __restrict__ WT,
                                                       int N) {
  __shared__ unsigned short t[64][65];
  const int n0 = blockIdx.x * 64;
  const int k0 = blockIdx.y * 64;
  const int tid = threadIdx.x;
#pragma unroll
  for (int i = 0; i < 16; i++) {
    int li = tid + i * 256;
    int kk = li >> 6, nn = li & 63;
    t[kk][nn] = f2bf(W[(size_t)(k0 + kk) * N + (n0 + nn)]);
  }
  __syncthreads();
#pragma unroll
  for (int i = 0; i < 16; i++) {
    int li = tid + i * 256;
    int nn = li >> 6, kk = li & 63;
    WT[(size_t)(n0 + nn) * 2048 + (k0 + kk)] = t[kk][nn];
  }
}

// ---------------- GEMM: C[128x128] per block, A[M][2048] bf16, Bt[N][2048] bf16
// MODE 0: qkv epilogue (+bias, scatter q/k natural, v transposed)
// MODE 1: fp32 out[M][2048]
template <int MODE>
__global__ __launch_bounds__(256) void k_gemm(const unsigned short* __restrict__ A,
                                              const unsigned short* __restrict__ Bt,
                                              const float* __restrict__ bias,
                                              unsigned short* __restrict__ qb,
                                              unsigned short* __restrict__ kb,
                                              unsigned short* __restrict__ vtb,
                                              float* __restrict__ outp) {
  __shared__ __align__(16) unsigned short As[128 * 64];
  __shared__ __align__(16) unsigned short Bs[128 * 64];
  const int tid = threadIdx.x;
  const int lane = tid & 63, wid = tid >> 6;
  const int quad = lane >> 4, l16 = lane & 15;
  const int wm = wid >> 1, wn = wid & 1;
  const int m0 = blockIdx.y * 128, n0 = blockIdx.x * 128;

  f32x4 acc[4][4];
#pragma unroll
  for (int i = 0; i < 4; i++)
#pragma unroll
    for (int j = 0; j < 4; j++) {
      f32x4 z = {0.f, 0.f, 0.f, 0.f};
      acc[i][j] = z;
    }

  for (int k0 = 0; k0 < 2048; k0 += 64) {
    __syncthreads();
#pragma unroll
    for (int i = 0; i < 4; i++) {
      int li = tid + i * 256;
      int row = li >> 3, ch = li & 7;
      bf16x8 va = *reinterpret_cast<const bf16x8*>(A + (size_t)(m0 + row) * 2048 + k0 + ch * 8);
      *reinterpret_cast<bf16x8*>(&As[row * 64 + ((ch ^ (row & 7)) * 8)]) = va;
      bf16x8 vb = *reinterpret_cast<const bf16x8*>(Bt + (size_t)(n0 + row) * 2048 + k0 + ch * 8);
      *reinterpret_cast<bf16x8*>(&Bs[row * 64 + ((ch ^ (row & 7)) * 8)]) = vb;
    }
    __syncthreads();
#pragma unroll
    for (int kc = 0; kc < 2; kc++) {
      bf16x8 af[4], bfr[4];
#pragma unroll
      for (int mt = 0; mt < 4; mt++) {
        int r = wm * 64 + mt * 16 + l16;
        int ch = kc * 4 + quad;
        af[mt] = *reinterpret_cast<const bf16x8*>(&As[r * 64 + ((ch ^ (r & 7)) * 8)]);
      }
#pragma unroll
      for (int nt = 0; nt < 4; nt++) {
        int r = wn * 64 + nt * 16 + l16;
        int ch = kc * 4 + quad;
        bfr[nt] = *reinterpret_cast<const bf16x8*>(&Bs[r * 64 + ((ch ^ (r & 7)) * 8)]);
      }
#pragma unroll
      for (int mt = 0; mt < 4; mt++)
#pragma unroll
        for (int nt = 0; nt < 4; nt++)
          acc[mt][nt] = MFMA16(af[mt], bfr[nt], acc[mt][nt]);
    }
  }

  const int mbase = m0 + wm * 64;
  const int nbase = n0 + wn * 64;
  if (MODE == 0) {
#pragma unroll
    for (int nt = 0; nt < 4; nt++) {
      int n = nbase + nt * 16 + l16;
      float bv = bias[n];
      int seg = n >> 11;         // 0=q,1=k,2=v
      int h = (n >> 7) & 15;
      int d = n & 127;
#pragma unroll
      for (int mt = 0; mt < 4; mt++) {
        int mrow = mbase + mt * 16 + quad * 4;
        int b = mrow >> 11, s = mrow & 2047;
        if (seg == 2) {
          ushort4_ pk;
          pk.x = f2bf(acc[mt][nt][0] + bv);
          pk.y = f2bf(acc[mt][nt][1] + bv);
          pk.z = f2bf(acc[mt][nt][2] + bv);
          pk.w = f2bf(acc[mt][nt][3] + bv);
          *reinterpret_cast<ushort4_*>(vtb + ((size_t)(b * 16 + h) * 128 + d) * 2048 + s) = pk;
        } else {
          unsigned short* dst = (seg == 0 ? qb : kb);
          size_t base = (size_t)(b * 16 + h) * 2048;
#pragma unroll
          for (int rg = 0; rg < 4; rg++)
            dst[(base + (s + rg)) * 128 + d] = f2bf(acc[mt][nt][rg] + bv);
        }
      }
    }
  } else {
#pragma unroll
    for (int nt = 0; nt < 4; nt++) {
      int n = nbase + nt * 16 + l16;
#pragma unroll
      for (int mt = 0; mt < 4; mt++) {
        int mrow = mbase + mt * 16 + quad * 4;
#pragma unroll
        for (int rg = 0; rg < 4; rg++)
          outp[(size_t)(mrow + rg) * 2048 + n] = acc[mt][nt][rg];
      }
    }
  }
}

// ---------------- flash attention: 128 q-rows x one (b,h) per block ----------------
__global__ __launch_bounds__(256) void k_attn(const unsigned short* __restrict__ qb,
                                              const unsigned short* __restrict__ kb,
                                              const unsigned short* __restrict__ vtb,
                                              unsigned short* __restrict__ ctx) {
  __shared__ __align__(16) unsigned short Ks[64 * 128];  // [key][dim] swizzled
  __shared__ __align__(16) unsigned short Vs[128 * 64];  // [dim][key] swizzled
  __shared__ __align__(16) unsigned short Ps[128 * 64];  // [qrow][key] swizzled
  const int qt = blockIdx.x, bh = blockIdx.y;
  const int tid = threadIdx.x;
  const int lane = tid & 63, w = tid >> 6;
  const int quad = lane >> 4, l16 = lane & 15;
  const int qbase = qt * 128;
  const unsigned short* Qh = qb + (size_t)bh * 2048 * 128;
  const unsigned short* Kh = kb + (size_t)bh * 2048 * 128;
  const unsigned short* Vh = vtb + (size_t)bh * 128 * 2048;

  bf16x8 qf[2][4];
#pragma unroll
  for (int mt = 0; mt < 2; mt++)
#pragma unroll
    for (int kc = 0; kc < 4; kc++)
      qf[mt][kc] = *reinterpret_cast<const bf16x8*>(
          Qh + (size_t)(qbase + w * 32 + mt * 16 + l16) * 128 + kc * 32 + quad * 8);

  f32x4 o[2][8];
#pragma unroll
  for (int mt = 0; mt < 2; mt++)
#pragma unroll
    for (int dt = 0; dt < 8; dt++) {
      f32x4 z = {0.f, 0.f, 0.f, 0.f};
      o[mt][dt] = z;
    }
  float m_run[2][4], l_run[2][4];
#pragma unroll
  for (int mt = 0; mt < 2; mt++)
#pragma unroll
    for (int rg = 0; rg < 4; rg++) { m_run[mt][rg] = -1e30f; l_run[mt][rg] = 0.f; }

  const int q_lo = qbase + w * 32;
  const int nkv = qt * 2 + 2;
  const float sl2 = 0.12751741f;  // (1/sqrt(128)) * log2(e)

  for (int kv = 0; kv < nkv; kv++) {
    const int kvb = kv * 64;
    __syncthreads();
#pragma unroll
    for (int i = 0; i < 4; i++) {
      int li = tid + i * 256;
      int row = li >> 4, ch = li & 15;
      *reinterpret_cast<bf16x8*>(&Ks[row * 128 + ((ch ^ (row & 7)) * 8)]) =
          *reinterpret_cast<const bf16x8*>(Kh + (size_t)(kvb + row) * 128 + ch * 8);
      int row2 = li >> 3, ch2 = li & 7;
      *reinterpret_cast<bf16x8*>(&Vs[row2 * 64 + ((ch2 ^ (row2 & 7)) * 8)]) =
          *reinterpret_cast<const bf16x8*>(Vh + (size_t)row2 * 2048 + kvb + ch2 * 8);
    }
    __syncthreads();
    if (kvb > q_lo + 31) continue;  // fully masked for this wave (barriers already passed)

    f32x4 sacc[2][4];
#pragma unroll
    for (int mt = 0; mt < 2; mt++)
#pragma unroll
      for (int nt = 0; nt < 4; nt++) {
        f32x4 z = {0.f, 0.f, 0.f, 0.f};
        sacc[mt][nt] = z;
      }
#pragma unroll
    for (int kc = 0; kc < 4; kc++) {
      bf16x8 kf[4];
#pragma unroll
      for (int nt = 0; nt < 4; nt++) {
        int r = nt * 16 + l16, ch = kc * 4 + quad;
        kf[nt] = *reinterpret_cast<const bf16x8*>(&Ks[r * 128 + ((ch ^ (r & 7)) * 8)]);
      }
#pragma unroll
      for (int mt = 0; mt < 2; mt++)
#pragma unroll
        for (int nt = 0; nt < 4; nt++)
          sacc[mt][nt] = MFMA16(qf[mt][kc], kf[nt], sacc[mt][nt]);
    }

    const bool needmask = (kvb + 63) > q_lo;
#pragma unroll
    for (int mt = 0; mt < 2; mt++) {
#pragma unroll
      for (int rg = 0; rg < 4; rg++) {
        int qr = q_lo + mt * 16 + quad * 4 + rg;
        float vals[4];
#pragma unroll
        for (int nt = 0; nt < 4; nt++) {
          float v = sacc[mt][nt][rg] * sl2;
          if (needmask && (kvb + nt * 16 + l16) > qr) v = -1e30f;
          vals[nt] = v;
        }
        float rmax = fmaxf(fmaxf(vals[0], vals[1]), fmaxf(vals[2], vals[3]));
#pragma unroll
        for (int off = 1; off < 16; off <<= 1)
          rmax = fmaxf(rmax, __shfl_xor(rmax, off));
        float mold = m_run[mt][rg];
        float mnew = fmaxf(mold, rmax);
        float alpha = exp2f(mold - mnew);
        m_run[mt][rg] = mnew;
        float rsum = 0.f;
#pragma unroll
        for (int nt = 0; nt < 4; nt++) {
          float p = exp2f(vals[nt] - mnew);
          sacc[mt][nt][rg] = p;
          rsum += p;
        }
#pragma unroll
        for (int off = 1; off < 16; off <<= 1)
          rsum += __shfl_xor(rsum, off);
        l_run[mt][rg] = l_run[mt][rg] * alpha + rsum;
#pragma unroll
        for (int dt = 0; dt < 8; dt++) o[mt][dt][rg] *= alpha;
      }
    }

    // P: C-layout -> LDS (per-wave region, no cross-wave sharing)
#pragma unroll
    for (int mt = 0; mt < 2; mt++)
#pragma unroll
      for (int nt = 0; nt < 4; nt++)
#pragma unroll
        for (int rg = 0; rg < 4; rg++) {
          int r = w * 32 + mt * 16 + quad * 4 + rg;
          int col = nt * 16 + l16;
          Ps[r * 64 + (((col >> 3) ^ (r & 7)) * 8) + (col & 7)] = f2bf(sacc[mt][nt][rg]);
        }
    asm volatile("s_waitcnt lgkmcnt(0)" ::: "memory");  // same-wave LDS RAW across lanes
    bf16x8 pf[2][2];
#pragma unroll
    for (int mt = 0; mt < 2; mt++)
#pragma unroll
      for (int kc = 0; kc < 2; kc++) {
        int r = w * 32 + mt * 16 + l16, ch = kc * 4 + quad;
        pf[mt][kc] = *reinterpret_cast<const bf16x8*>(&Ps[r * 64 + ((ch ^ (r & 7)) * 8)]);
      }
#pragma unroll
    for (int kc = 0; kc < 2; kc++)
#pragma unroll
      for (int dt = 0; dt < 8; dt++) {
        int r = dt * 16 + l16, ch = kc * 4 + quad;
        bf16x8 vf = *reinterpret_cast<const bf16x8*>(&Vs[r * 64 + ((ch ^ (r & 7)) * 8)]);
#pragma unroll
        for (int mt = 0; mt < 2; mt++)
          o[mt][dt] = MFMA16(pf[mt][kc], vf, o[mt][dt]);
      }
  }

  const int b = bh >> 4, h = bh & 15;
#pragma unroll
  for (int mt = 0; mt < 2; mt++) {
    float inv[4];
#pragma unroll
    for (int rg = 0; rg < 4; rg++) inv[rg] = 1.f / l_run[mt][rg];
#pragma unroll
    for (int dt = 0; dt < 8; dt++) {
      int col = h * 128 + dt * 16 + l16;
#pragma unroll
      for (int rg = 0; rg < 4; rg++) {
        int s = qbase + w * 32 + mt * 16 + quad * 4 + rg;
        ctx[((size_t)b * 2048 + s) * 2048 + col] = f2bf(o[mt][dt][rg] * inv[rg]);
      }
    }
  }
}

extern "C" void kernel_launch(void* const* d_in, const int* in_sizes, int n_in,
                              void* d_out, int out_size, void* d_ws, size_t ws_size,
                              hipStream_t stream) {
  const float* x = (const float*)d_in[0];
  const float* w_qkv = (const float*)d_in[1];
  const float* b_qkv = (const float*)d_in[2];
  const float* w_o = (const float*)d_in[3];
  float* outp = (float*)d_out;

  unsigned short* ws = (unsigned short*)d_ws;
  unsigned short* xb    = ws;                    // 8388608 el  (x as bf16)
  unsigned short* wqkvT = xb + 8388608;          // 12582912 el (w_qkv^T bf16 [6144][2048])
  unsigned short* woT   = wqkvT + 12582912;      // 4194304 el  (w_o^T bf16 [2048][2048])
  unsigned short* qbuf  = woT + 4194304;         // 8388608 el  q [b][h][s][d]
  unsigned short* kbuf  = qbuf + 8388608;        // 8388608 el  k [b][h][s][d]
  unsigned short* vtbuf = kbuf + 8388608;        // 8388608 el  v^T [b][h][d][s]
  unsigned short* ctxb  = vtbuf + 8388608;       // 8388608 el  ctx bf16 [4096][2048]
  // total 117,440,512 bytes

  k_cvt<<<8192, 256, 0, stream>>>(x, xb);
  k_transpose_cvt<<<dim3(96, 32), 256, 0, stream>>>(w_qkv, wqkvT, 6144);
  k_transpose_cvt<<<dim3(32, 32), 256, 0, stream>>>(w_o, woT, 2048);
  k_gemm<0><<<dim3(48, 32), 256, 0, stream>>>(xb, wqkvT, b_qkv, qbuf, kbuf, vtbuf, nullptr);
  k_attn<<<dim3(16, 32), 256, 0, stream>>>(qbuf, kbuf, vtbuf, ctxb);
  k_gemm<1><<<dim3(16, 32), 256, 0, stream>>>(ctxb, woT, nullptr, nullptr, nullptr, nullptr, outp);
}

// Round 2
// 550.482 us; speedup vs baseline: 1.1345x; 1.1345x over previous
//
#include <hip/hip_runtime.h>
#include <cstdint>
#include <cstddef>

typedef __attribute__((ext_vector_type(8))) short bf16x8;
typedef __attribute__((ext_vector_type(4))) float f32x4;
typedef __attribute__((ext_vector_type(4))) unsigned short ushort4_;

#define MFMA16(a, b, c) __builtin_amdgcn_mfma_f32_16x16x32_bf16((a), (b), (c), 0, 0, 0)

__device__ __forceinline__ unsigned short f2bf(float f) {
  union { float f; unsigned u; } c; c.f = f;
  unsigned r = c.u + 0x7fffu + ((c.u >> 16) & 1u);
  return (unsigned short)(r >> 16);
}

// async global->LDS, 16B per lane. lds ptr MUST be wave-uniform; HW writes
// lane i at lds + i*16 (m97/m104 semantics). Swizzle goes in the SOURCE addr.
__device__ __forceinline__ void gl_lds16(const unsigned short* g, unsigned short* l) {
  __builtin_amdgcn_global_load_lds(
      (const __attribute__((address_space(1))) void*)g,
      (__attribute__((address_space(3))) void*)l, 16, 0, 0);
}

// ---------------- fp32 -> bf16 ----------------
__global__ __launch_bounds__(256) void k_cvt(const float* __restrict__ x,
                                             unsigned short* __restrict__ y) {
  int i = blockIdx.x * 256 + threadIdx.x;
  float4 v = reinterpret_cast<const float4*>(x)[i];
  ushort4_ o;
  o.x = f2bf(v.x); o.y = f2bf(v.y); o.z = f2bf(v.z); o.w = f2bf(v.w);
  reinterpret_cast<ushort4_*>(y)[i] = o;
}

// ---------------- W[K=2048][N] fp32 -> WT[N][2048] bf16 ----------------
__global__ __launch_bounds__(256) void k_transpose_cvt(const float* __restrict__ W,
                                                       unsigned short* __restrict__ WT,
                                                       int N) {
  __shared__ unsigned short t[64][65];
  const int n0 = blockIdx.x * 64;
  const int k0 = blockIdx.y * 64;
  const int tid = threadIdx.x;
#pragma unroll
  for (int i = 0; i < 16; i++) {
    int li = tid + i * 256;
    int kk = li >> 6, nn = li & 63;
    t[kk][nn] = f2bf(W[(size_t)(k0 + kk) * N + (n0 + nn)]);
  }
  __syncthreads();
#pragma unroll
  for (int i = 0; i < 16; i++) {
    int li = tid + i * 256;
    int nn = li >> 6, kk = li & 63;
    WT[(size_t)(n0 + nn) * 2048 + (k0 + kk)] = t[kk][nn];
  }
}

// ---------------- GEMM: C[128x128]/block, A[M][2048] bf16, Bt[N][2048] bf16
// MODE 0: qkv epilogue (+bias, scatter q/k natural, v transposed)
// MODE 1: fp32 out[M][2048]
template <int MODE>
__global__ __launch_bounds__(256) void k_gemm(const unsigned short* __restrict__ A,
                                              const unsigned short* __restrict__ Bt,
                                              const float* __restrict__ bias,
                                              unsigned short* __restrict__ qb,
                                              unsigned short* __restrict__ kb,
                                              unsigned short* __restrict__ vtb,
                                              float* __restrict__ outp) {
  __shared__ __align__(16) unsigned short As[128 * 64];
  __shared__ __align__(16) unsigned short Bs[128 * 64];
  const int tid = threadIdx.x;
  const int lane = tid & 63, wid = tid >> 6;
  const int quad = lane >> 4, l16 = lane & 15;
  const int wm = wid >> 1, wn = wid & 1;
  const int m0 = blockIdx.y * 128, n0 = blockIdx.x * 128;

  f32x4 acc[4][4];
#pragma unroll
  for (int i = 0; i < 4; i++)
#pragma unroll
    for (int j = 0; j < 4; j++) {
      f32x4 z = {0.f, 0.f, 0.f, 0.f};
      acc[i][j] = z;
    }

  for (int k0 = 0; k0 < 2048; k0 += 64) {
    __syncthreads();
#pragma unroll
    for (int i = 0; i < 4; i++) {
      int slotbase = wid * 64 + i * 256;
      int slot = slotbase + lane;
      int row = slot >> 3, chs = slot & 7, gch = chs ^ (row & 7);
      gl_lds16(A + (size_t)(m0 + row) * 2048 + k0 + gch * 8, &As[slotbase * 8]);
      gl_lds16(Bt + (size_t)(n0 + row) * 2048 + k0 + gch * 8, &Bs[slotbase * 8]);
    }
    __syncthreads();
#pragma unroll
    for (int kc = 0; kc < 2; kc++) {
      bf16x8 af[4], bfr[4];
#pragma unroll
      for (int mt = 0; mt < 4; mt++) {
        int r = wm * 64 + mt * 16 + l16;
        int ch = kc * 4 + quad;
        af[mt] = *reinterpret_cast<const bf16x8*>(&As[r * 64 + ((ch ^ (r & 7)) * 8)]);
      }
#pragma unroll
      for (int nt = 0; nt < 4; nt++) {
        int r = wn * 64 + nt * 16 + l16;
        int ch = kc * 4 + quad;
        bfr[nt] = *reinterpret_cast<const bf16x8*>(&Bs[r * 64 + ((ch ^ (r & 7)) * 8)]);
      }
#pragma unroll
      for (int mt = 0; mt < 4; mt++)
#pragma unroll
        for (int nt = 0; nt < 4; nt++)
          acc[mt][nt] = MFMA16(af[mt], bfr[nt], acc[mt][nt]);
    }
  }

  const int mbase = m0 + wm * 64;
  const int nbase = n0 + wn * 64;
  if (MODE == 0) {
#pragma unroll
    for (int nt = 0; nt < 4; nt++) {
      int n = nbase + nt * 16 + l16;
      float bv = bias[n];
      int seg = n >> 11;  // 0=q,1=k,2=v
      int h = (n >> 7) & 15;
      int d = n & 127;
#pragma unroll
      for (int mt = 0; mt < 4; mt++) {
        int mrow = mbase + mt * 16 + quad * 4;
        int b = mrow >> 11, s = mrow & 2047;
        if (seg == 2) {
          ushort4_ pk;
          pk.x = f2bf(acc[mt][nt][0] + bv);
          pk.y = f2bf(acc[mt][nt][1] + bv);
          pk.z = f2bf(acc[mt][nt][2] + bv);
          pk.w = f2bf(acc[mt][nt][3] + bv);
          *reinterpret_cast<ushort4_*>(vtb + ((size_t)(b * 16 + h) * 128 + d) * 2048 + s) = pk;
        } else {
          unsigned short* dst = (seg == 0 ? qb : kb);
          size_t base = (size_t)(b * 16 + h) * 2048;
#pragma unroll
          for (int rg = 0; rg < 4; rg++)
            dst[(base + (s + rg)) * 128 + d] = f2bf(acc[mt][nt][rg] + bv);
        }
      }
    }
  } else {
#pragma unroll
    for (int nt = 0; nt < 4; nt++) {
      int n = nbase + nt * 16 + l16;
#pragma unroll
      for (int mt = 0; mt < 4; mt++) {
        int mrow = mbase + mt * 16 + quad * 4;
#pragma unroll
        for (int rg = 0; rg < 4; rg++)
          outp[(size_t)(mrow + rg) * 2048 + n] = acc[mt][nt][rg];
      }
    }
  }
}

// ---------------- flash attention: 64 q-rows x one (b,h) per block ----------------
// 4 waves x 16 q-rows each; KV tiles of 64; qt reversed so longest blocks start first.
__global__ __launch_bounds__(256, 4) void k_attn(const unsigned short* __restrict__ qb,
                                                 const unsigned short* __restrict__ kb,
                                                 const unsigned short* __restrict__ vtb,
                                                 unsigned short* __restrict__ ctx) {
  __shared__ __align__(16) unsigned short Ks[64 * 128];  // [key][dim] swizzled, 16KB
  __shared__ __align__(16) unsigned short Vs[128 * 64];  // [dim][key] swizzled, 16KB
  __shared__ __align__(16) unsigned short Ps[64 * 64];   // [qrow][key] swizzled, 8KB
  const int qt = (gridDim.x - 1) - blockIdx.x;  // longest first
  const int bh = blockIdx.y;
  const int tid = threadIdx.x;
  const int lane = tid & 63, w = tid >> 6;
  const int quad = lane >> 4, l16 = lane & 15;
  const int qbase = qt * 64;
  const unsigned short* Qh = qb + (size_t)bh * 2048 * 128;
  const unsigned short* Kh = kb + (size_t)bh * 2048 * 128;
  const unsigned short* Vh = vtb + (size_t)bh * 128 * 2048;

  bf16x8 qf[4];
#pragma unroll
  for (int kc = 0; kc < 4; kc++)
    qf[kc] = *reinterpret_cast<const bf16x8*>(
        Qh + (size_t)(qbase + w * 16 + l16) * 128 + kc * 32 + quad * 8);

  f32x4 o[8];
#pragma unroll
  for (int dt = 0; dt < 8; dt++) {
    f32x4 z = {0.f, 0.f, 0.f, 0.f};
    o[dt] = z;
  }
  float m_run[4], l_run[4];
#pragma unroll
  for (int rg = 0; rg < 4; rg++) { m_run[rg] = -1e30f; l_run[rg] = 0.f; }

  const int q_lo = qbase + w * 16;
  const int nkv = qt + 1;
  const float sl2 = 0.12751741f;  // (1/sqrt(128)) * log2(e)

  for (int kv = 0; kv < nkv; kv++) {
    const int kvb = kv * 64;
    __syncthreads();
    // stage K tile (64 keys x 128d) and V^T tile (128d x 64 keys) via async LDS
#pragma unroll
    for (int i = 0; i < 4; i++) {
      int slotbase = w * 64 + i * 256;
      int slot = slotbase + lane;
      int rowk = slot >> 4, chk = (slot & 15) ^ (rowk & 7);
      gl_lds16(Kh + (size_t)(kvb + rowk) * 128 + chk * 8, &Ks[slotbase * 8]);
      int rowv = slot >> 3, chv = (slot & 7) ^ (rowv & 7);
      gl_lds16(Vh + (size_t)rowv * 2048 + kvb + chv * 8, &Vs[slotbase * 8]);
    }
    __syncthreads();
    if (kvb > q_lo + 15) continue;  // fully masked for this wave

    // S = Q K^T
    f32x4 sacc[4];
#pragma unroll
    for (int nt = 0; nt < 4; nt++) {
      f32x4 z = {0.f, 0.f, 0.f, 0.f};
      sacc[nt] = z;
    }
#pragma unroll
    for (int kc = 0; kc < 4; kc++) {
      bf16x8 kf[4];
#pragma unroll
      for (int nt = 0; nt < 4; nt++) {
        int r = nt * 16 + l16, ch = kc * 4 + quad;
        kf[nt] = *reinterpret_cast<const bf16x8*>(&Ks[r * 128 + ((ch ^ (r & 7)) * 8)]);
      }
#pragma unroll
      for (int nt = 0; nt < 4; nt++)
        sacc[nt] = MFMA16(qf[kc], kf[nt], sacc[nt]);
    }

    // online softmax (rows: quad*4+rg within wave's 16)
    const bool needmask = (kvb + 63) > q_lo;
#pragma unroll
    for (int rg = 0; rg < 4; rg++) {
      int qr = q_lo + quad * 4 + rg;
      float vals[4];
#pragma unroll
      for (int nt = 0; nt < 4; nt++) {
        float v = sacc[nt][rg] * sl2;
        if (needmask && (kvb + nt * 16 + l16) > qr) v = -1e30f;
        vals[nt] = v;
      }
      float rmax = fmaxf(fmaxf(vals[0], vals[1]), fmaxf(vals[2], vals[3]));
#pragma unroll
      for (int off = 1; off < 16; off <<= 1)
        rmax = fmaxf(rmax, __shfl_xor(rmax, off));
      float mold = m_run[rg];
      float mnew = fmaxf(mold, rmax);
      float alpha = exp2f(mold - mnew);
      m_run[rg] = mnew;
      float rsum = 0.f;
#pragma unroll
      for (int nt = 0; nt < 4; nt++) {
        float p = exp2f(vals[nt] - mnew);
        sacc[nt][rg] = p;
        rsum += p;
      }
#pragma unroll
      for (int off = 1; off < 16; off <<= 1)
        rsum += __shfl_xor(rsum, off);
      l_run[rg] = l_run[rg] * alpha + rsum;
#pragma unroll
      for (int dt = 0; dt < 8; dt++) o[dt][rg] *= alpha;
    }

    // P: C-layout -> LDS (per-wave rows, same-wave consumer)
#pragma unroll
    for (int nt = 0; nt < 4; nt++)
#pragma unroll
      for (int rg = 0; rg < 4; rg++) {
        int r = w * 16 + quad * 4 + rg;
        int col = nt * 16 + l16;
        Ps[r * 64 + (((col >> 3) ^ (r & 7)) * 8) + (col & 7)] = f2bf(sacc[nt][rg]);
      }
    asm volatile("s_waitcnt lgkmcnt(0)" ::: "memory");
    bf16x8 pf[2];
#pragma unroll
    for (int kc = 0; kc < 2; kc++) {
      int r = w * 16 + l16, ch = kc * 4 + quad;
      pf[kc] = *reinterpret_cast<const bf16x8*>(&Ps[r * 64 + ((ch ^ (r & 7)) * 8)]);
    }
#pragma unroll
    for (int kc = 0; kc < 2; kc++)
#pragma unroll
      for (int dt = 0; dt < 8; dt++) {
        int r = dt * 16 + l16, ch = kc * 4 + quad;
        bf16x8 vf = *reinterpret_cast<const bf16x8*>(&Vs[r * 64 + ((ch ^ (r & 7)) * 8)]);
        o[dt] = MFMA16(pf[kc], vf, o[dt]);
      }
  }

  const int b = bh >> 4, h = bh & 15;
  float inv[4];
#pragma unroll
  for (int rg = 0; rg < 4; rg++) inv[rg] = 1.f / l_run[rg];
#pragma unroll
  for (int dt = 0; dt < 8; dt++) {
    int col = h * 128 + dt * 16 + l16;
#pragma unroll
    for (int rg = 0; rg < 4; rg++) {
      int s = qbase + w * 16 + quad * 4 + rg;
      ctx[((size_t)b * 2048 + s) * 2048 + col] = f2bf(o[dt][rg] * inv[rg]);
    }
  }
}

extern "C" void kernel_launch(void* const* d_in, const int* in_sizes, int n_in,
                              void* d_out, int out_size, void* d_ws, size_t ws_size,
                              hipStream_t stream) {
  const float* x = (const float*)d_in[0];
  const float* w_qkv = (const float*)d_in[1];
  const float* b_qkv = (const float*)d_in[2];
  const float* w_o = (const float*)d_in[3];
  float* outp = (float*)d_out;

  unsigned short* ws = (unsigned short*)d_ws;
  unsigned short* xb    = ws;
  unsigned short* wqkvT = xb + 8388608;
  unsigned short* woT   = wqkvT + 12582912;
  unsigned short* qbuf  = woT + 4194304;
  unsigned short* kbuf  = qbuf + 8388608;
  unsigned short* vtbuf = kbuf + 8388608;
  unsigned short* ctxb  = vtbuf + 8388608;
  // total ~117.4 MB

  k_cvt<<<8192, 256, 0, stream>>>(x, xb);
  k_transpose_cvt<<<dim3(96, 32), 256, 0, stream>>>(w_qkv, wqkvT, 6144);
  k_transpose_cvt<<<dim3(32, 32), 256, 0, stream>>>(w_o, woT, 2048);
  k_gemm<0><<<dim3(48, 32), 256, 0, stream>>>(xb, wqkvT, b_qkv, qbuf, kbuf, vtbuf, nullptr);
  k_attn<<<dim3(32, 32), 256, 0, stream>>>(qbuf, kbuf, vtbuf, ctxb);
  k_gemm<1><<<dim3(16, 32), 256, 0, stream>>>(ctxb, woT, nullptr, nullptr, nullptr, nullptr, outp);
}

// Round 4
// 466.327 us; speedup vs baseline: 1.3393x; 1.1805x over previous
//
#include <hip/hip_runtime.h>
#include <cstdint>
#include <cstddef>

typedef __attribute__((ext_vector_type(8))) short bf16x8;
typedef __attribute__((ext_vector_type(4))) float f32x4;
typedef __attribute__((ext_vector_type(4))) unsigned short ushort4_;

#define MFMA16(a, b, c) __builtin_amdgcn_mfma_f32_16x16x32_bf16((a), (b), (c), 0, 0, 0)

__device__ __forceinline__ unsigned short f2bf(float f) {
  union { float f; unsigned u; } c; c.f = f;
  unsigned r = c.u + 0x7fffu + ((c.u >> 16) & 1u);
  return (unsigned short)(r >> 16);
}

// async global->LDS, 16B per lane. LDS ptr must be wave-uniform; HW writes
// lane i at lds + i*16 (m97/m104). Swizzle goes into the SOURCE address.
__device__ __forceinline__ void gl_lds16(const unsigned short* g, unsigned short* l) {
  __builtin_amdgcn_global_load_lds(
      (const __attribute__((address_space(1))) void*)g,
      (__attribute__((address_space(3))) void*)l, 16, 0, 0);
}

// ---------------- fp32 -> bf16 ----------------
__global__ __launch_bounds__(256) void k_cvt(const float* __restrict__ x,
                                             unsigned short* __restrict__ y) {
  int i = blockIdx.x * 256 + threadIdx.x;
  float4 v = reinterpret_cast<const float4*>(x)[i];
  ushort4_ o;
  o.x = f2bf(v.x); o.y = f2bf(v.y); o.z = f2bf(v.z); o.w = f2bf(v.w);
  reinterpret_cast<ushort4_*>(y)[i] = o;
}

// ---------------- W[K=2048][N] fp32 -> WT[N][2048] bf16 ----------------
__global__ __launch_bounds__(256) void k_transpose_cvt(const float* __restrict__ W,
                                                       unsigned short* __restrict__ WT,
                                                       int N) {
  __shared__ unsigned short t[64][65];
  const int n0 = blockIdx.x * 64;
  const int k0 = blockIdx.y * 64;
  const int tid = threadIdx.x;
#pragma unroll
  for (int i = 0; i < 16; i++) {
    int li = tid + i * 256;
    int kk = li >> 6, nn = li & 63;
    t[kk][nn] = f2bf(W[(size_t)(k0 + kk) * N + (n0 + nn)]);
  }
  __syncthreads();
#pragma unroll
  for (int i = 0; i < 16; i++) {
    int li = tid + i * 256;
    int nn = li >> 6, kk = li & 63;
    WT[(size_t)(n0 + nn) * 2048 + (k0 + kk)] = t[kk][nn];
  }
}

// ---------------- GEMM: C[128x128]/block, A[M][2048] bf16, Bt[N][2048] bf16
template <int MODE>
__global__ __launch_bounds__(256) void k_gemm(const unsigned short* __restrict__ A,
                                              const unsigned short* __restrict__ Bt,
                                              const float* __restrict__ bias,
                                              unsigned short* __restrict__ qb,
                                              unsigned short* __restrict__ kb,
                                              unsigned short* __restrict__ vtb,
                                              float* __restrict__ outp) {
  __shared__ __align__(16) unsigned short As[128 * 64];
  __shared__ __align__(16) unsigned short Bs[128 * 64];
  const int tid = threadIdx.x;
  const int lane = tid & 63, wid = tid >> 6;
  const int quad = lane >> 4, l16 = lane & 15;
  const int wm = wid >> 1, wn = wid & 1;
  const int m0 = blockIdx.y * 128, n0 = blockIdx.x * 128;

  f32x4 acc[4][4];
#pragma unroll
  for (int i = 0; i < 4; i++)
#pragma unroll
    for (int j = 0; j < 4; j++) {
      f32x4 z = {0.f, 0.f, 0.f, 0.f};
      acc[i][j] = z;
    }

  for (int k0 = 0; k0 < 2048; k0 += 64) {
    __syncthreads();
#pragma unroll
    for (int i = 0; i < 4; i++) {
      int slotbase = wid * 64 + i * 256;
      int slot = slotbase + lane;
      int row = slot >> 3, chs = slot & 7, gch = chs ^ (row & 7);
      gl_lds16(A + (size_t)(m0 + row) * 2048 + k0 + gch * 8, &As[slotbase * 8]);
      gl_lds16(Bt + (size_t)(n0 + row) * 2048 + k0 + gch * 8, &Bs[slotbase * 8]);
    }
    __syncthreads();
#pragma unroll
    for (int kc = 0; kc < 2; kc++) {
      bf16x8 af[4], bfr[4];
#pragma unroll
      for (int mt = 0; mt < 4; mt++) {
        int r = wm * 64 + mt * 16 + l16;
        int ch = kc * 4 + quad;
        af[mt] = *reinterpret_cast<const bf16x8*>(&As[r * 64 + ((ch ^ (r & 7)) * 8)]);
      }
#pragma unroll
      for (int nt = 0; nt < 4; nt++) {
        int r = wn * 64 + nt * 16 + l16;
        int ch = kc * 4 + quad;
        bfr[nt] = *reinterpret_cast<const bf16x8*>(&Bs[r * 64 + ((ch ^ (r & 7)) * 8)]);
      }
#pragma unroll
      for (int mt = 0; mt < 4; mt++)
#pragma unroll
        for (int nt = 0; nt < 4; nt++)
          acc[mt][nt] = MFMA16(af[mt], bfr[nt], acc[mt][nt]);
    }
  }

  const int mbase = m0 + wm * 64;
  const int nbase = n0 + wn * 64;
  if (MODE == 0) {
#pragma unroll
    for (int nt = 0; nt < 4; nt++) {
      int n = nbase + nt * 16 + l16;
      float bv = bias[n];
      int seg = n >> 11;  // 0=q,1=k,2=v
      int h = (n >> 7) & 15;
      int d = n & 127;
#pragma unroll
      for (int mt = 0; mt < 4; mt++) {
        int mrow = mbase + mt * 16 + quad * 4;
        int b = mrow >> 11, s = mrow & 2047;
        if (seg == 2) {
          ushort4_ pk;
          pk.x = f2bf(acc[mt][nt][0] + bv);
          pk.y = f2bf(acc[mt][nt][1] + bv);
          pk.z = f2bf(acc[mt][nt][2] + bv);
          pk.w = f2bf(acc[mt][nt][3] + bv);
          *reinterpret_cast<ushort4_*>(vtb + ((size_t)(b * 16 + h) * 128 + d) * 2048 + s) = pk;
        } else {
          unsigned short* dst = (seg == 0 ? qb : kb);
          size_t base = (size_t)(b * 16 + h) * 2048;
#pragma unroll
          for (int rg = 0; rg < 4; rg++)
            dst[(base + (s + rg)) * 128 + d] = f2bf(acc[mt][nt][rg] + bv);
        }
      }
    }
  } else {
#pragma unroll
    for (int nt = 0; nt < 4; nt++) {
      int n = nbase + nt * 16 + l16;
#pragma unroll
      for (int mt = 0; mt < 4; mt++) {
        int mrow = mbase + mt * 16 + quad * 4;
#pragma unroll
        for (int rg = 0; rg < 4; rg++)
          outp[(size_t)(mrow + rg) * 2048 + n] = acc[mt][nt][rg];
      }
    }
  }
}

// ---------------- flash attention, S^T orientation + pipelined staging ----------------
// 64 q-rows per block, 4 waves x 16 rows. KV tiles of 64, double-buffered LDS.
// S^T = K·Q^T (swap MFMA operands): keys in regs, q in lanes -> in-lane softmax
// reductions (2 shfl rounds), per-lane m/l, O^T accumulation (uniform alpha).
// Ps rows are PER-WAVE: row = w*16 + l16 (R3 bug: missing w*16 -> cross-wave race).
__global__ __launch_bounds__(256) void k_attn(const unsigned short* __restrict__ qb,
                                              const unsigned short* __restrict__ kb,
                                              const unsigned short* __restrict__ vtb,
                                              unsigned short* __restrict__ ctx) {
  __shared__ __align__(16) unsigned short Ks[2][64 * 128];  // [buf][key][dim] 32KB
  __shared__ __align__(16) unsigned short Vs[2][128 * 64];  // [buf][dim][key] 32KB
  __shared__ __align__(16) unsigned short Ps[64 * 64];      // [q][key] 8KB
  const int qt = (gridDim.x - 1) - blockIdx.x;  // longest first
  const int bh = blockIdx.y;
  const int tid = threadIdx.x;
  const int lane = tid & 63, w = tid >> 6;
  const int quad = lane >> 4, l16 = lane & 15;
  const int qbase = qt * 64;
  const unsigned short* Qh = qb + (size_t)bh * 2048 * 128;
  const unsigned short* Kh = kb + (size_t)bh * 2048 * 128;
  const unsigned short* Vh = vtb + (size_t)bh * 128 * 2048;

  const int q_lo = qbase + w * 16;  // this wave's 16 q rows: q_lo + l16
  const int nkv = qt + 1;
  const float sl2 = 0.12751741f;  // (1/sqrt(128)) * log2(e)

  // Q fragments (b-operand layout: n=q at l16, k=d at kc*32+quad*8)
  bf16x8 qf[4];
#pragma unroll
  for (int kc = 0; kc < 4; kc++)
    qf[kc] = *reinterpret_cast<const bf16x8*>(
        Qh + (size_t)(q_lo + l16) * 128 + kc * 32 + quad * 8);

  // O^T accumulator: 8 d-tiles of 16, rows=d (quad*4+rg), cols=q (l16)
  f32x4 o[8];
#pragma unroll
  for (int dt = 0; dt < 8; dt++) {
    f32x4 z = {0.f, 0.f, 0.f, 0.f};
    o[dt] = z;
  }
  float m_run = -1e30f, l_run = 0.f;

  auto stage = [&](int kvb, int bsel) {
    unsigned short* Kd = &Ks[bsel][0];
    unsigned short* Vd = &Vs[bsel][0];
#pragma unroll
    for (int i = 0; i < 4; i++) {
      int slotbase = w * 64 + i * 256;
      int slot = slotbase + lane;
      int rowk = slot >> 4, chk = (slot & 15) ^ (rowk & 7);
      gl_lds16(Kh + (size_t)(kvb + rowk) * 128 + chk * 8, Kd + slotbase * 8);
      int rowv = slot >> 3, chv = (slot & 7) ^ (rowv & 7);
      gl_lds16(Vh + (size_t)rowv * 2048 + kvb + chv * 8, Vd + slotbase * 8);
    }
  };

  stage(0, 0);

  for (int kv = 0; kv < nkv; kv++) {
    const int kvb = kv * 64;
    const int cur = kv & 1;
    // own writes of buf[cur] (issued last iteration) must be complete; then
    // block-wide barrier. Prefetch of buf[cur^1] stays in flight across it.
    asm volatile("s_waitcnt vmcnt(0)" ::: "memory");
    asm volatile("s_barrier" ::: "memory");
    if (kv + 1 < nkv) stage(kvb + 64, cur ^ 1);
    if (kvb > q_lo + 15) continue;  // fully masked for this wave

    const unsigned short* Kc = &Ks[cur][0];
    const unsigned short* Vc = &Vs[cur][0];

    // S^T = K Q^T : rows=keys (quad*4+rg per nt tile), cols=q (l16)
    f32x4 sacc[4];
#pragma unroll
    for (int nt = 0; nt < 4; nt++) {
      f32x4 z = {0.f, 0.f, 0.f, 0.f};
      sacc[nt] = z;
    }
#pragma unroll
    for (int kc = 0; kc < 4; kc++) {
      bf16x8 kf[4];
#pragma unroll
      for (int nt = 0; nt < 4; nt++) {
        int r = nt * 16 + l16, ch = kc * 4 + quad;
        kf[nt] = *reinterpret_cast<const bf16x8*>(&Kc[r * 128 + ((ch ^ (r & 7)) * 8)]);
      }
#pragma unroll
      for (int nt = 0; nt < 4; nt++)
        sacc[nt] = MFMA16(kf[nt], qf[kc], sacc[nt]);
    }

    // online softmax: per-lane over 16 in-register keys + 2 shfl rounds
    const bool needmask = (kvb + 63) > q_lo;
    const int qabs = q_lo + l16;
    float tmax = -1e30f;
#pragma unroll
    for (int nt = 0; nt < 4; nt++)
#pragma unroll
      for (int rg = 0; rg < 4; rg++) {
        float v = sacc[nt][rg] * sl2;
        if (needmask && (kvb + nt * 16 + quad * 4 + rg) > qabs) v = -1e30f;
        sacc[nt][rg] = v;
        tmax = fmaxf(tmax, v);
      }
    tmax = fmaxf(tmax, __shfl_xor(tmax, 16));
    tmax = fmaxf(tmax, __shfl_xor(tmax, 32));
    float mnew = fmaxf(m_run, tmax);
    float alpha = exp2f(m_run - mnew);
    m_run = mnew;
    float rsum = 0.f;
#pragma unroll
    for (int nt = 0; nt < 4; nt++)
#pragma unroll
      for (int rg = 0; rg < 4; rg++) {
        float p = exp2f(sacc[nt][rg] - mnew);
        sacc[nt][rg] = p;
        rsum += p;
      }
    rsum += __shfl_xor(rsum, 16);
    rsum += __shfl_xor(rsum, 32);
    l_run = l_run * alpha + rsum;
#pragma unroll
    for (int dt = 0; dt < 8; dt++)
#pragma unroll
      for (int rg = 0; rg < 4; rg++) o[dt][rg] *= alpha;

    // P^T (rows=keys, cols=q) -> Ps[q][key], per-wave rows w*16+l16,
    // vectorized 8B stores, 16B-chunk swizzle (row&7 == l16&7 since w*16 % 16 == 0)
#pragma unroll
    for (int nt = 0; nt < 4; nt++) {
      ushort4_ pk;
      pk.x = f2bf(sacc[nt][0]);
      pk.y = f2bf(sacc[nt][1]);
      pk.z = f2bf(sacc[nt][2]);
      pk.w = f2bf(sacc[nt][3]);
      int chunk = nt * 2 + (quad >> 1);
      *reinterpret_cast<ushort4_*>(
          &Ps[(w * 16 + l16) * 64 + ((chunk ^ (l16 & 7)) * 8) + (quad & 1) * 4]) = pk;
    }
    asm volatile("s_waitcnt lgkmcnt(0)" ::: "memory");  // same-wave rows only

    // O^T += V^T · P^T : A=V^T frag (m=d), B=P^T frag (n=q, k=key)
#pragma unroll
    for (int kc = 0; kc < 2; kc++) {
      int chunkr = kc * 4 + quad;
      bf16x8 pf = *reinterpret_cast<const bf16x8*>(
          &Ps[(w * 16 + l16) * 64 + ((chunkr ^ (l16 & 7)) * 8)]);
#pragma unroll
      for (int dt = 0; dt < 8; dt++) {
        int r = dt * 16 + l16, ch = kc * 4 + quad;
        bf16x8 vf = *reinterpret_cast<const bf16x8*>(&Vc[r * 64 + ((ch ^ (r & 7)) * 8)]);
        o[dt] = MFMA16(vf, pf, o[dt]);
      }
    }
  }

  const int b = bh >> 4, h = bh & 15;
  const float inv = 1.f / l_run;
  const int s = q_lo + l16;
#pragma unroll
  for (int dt = 0; dt < 8; dt++) {
    int d0 = dt * 16 + quad * 4;
    ushort4_ pk;
    pk.x = f2bf(o[dt][0] * inv);
    pk.y = f2bf(o[dt][1] * inv);
    pk.z = f2bf(o[dt][2] * inv);
    pk.w = f2bf(o[dt][3] * inv);
    *reinterpret_cast<ushort4_*>(
        &ctx[((size_t)b * 2048 + s) * 2048 + h * 128 + d0]) = pk;
  }
}

extern "C" void kernel_launch(void* const* d_in, const int* in_sizes, int n_in,
                              void* d_out, int out_size, void* d_ws, size_t ws_size,
                              hipStream_t stream) {
  const float* x = (const float*)d_in[0];
  const float* w_qkv = (const float*)d_in[1];
  const float* b_qkv = (const float*)d_in[2];
  const float* w_o = (const float*)d_in[3];
  float* outp = (float*)d_out;

  unsigned short* ws = (unsigned short*)d_ws;
  unsigned short* xb    = ws;
  unsigned short* wqkvT = xb + 8388608;
  unsigned short* woT   = wqkvT + 12582912;
  unsigned short* qbuf  = woT + 4194304;
  unsigned short* kbuf  = qbuf + 8388608;
  unsigned short* vtbuf = kbuf + 8388608;
  unsigned short* ctxb  = vtbuf + 8388608;
  // total ~117.4 MB

  k_cvt<<<8192, 256, 0, stream>>>(x, xb);
  k_transpose_cvt<<<dim3(96, 32), 256, 0, stream>>>(w_qkv, wqkvT, 6144);
  k_transpose_cvt<<<dim3(32, 32), 256, 0, stream>>>(w_o, woT, 2048);
  k_gemm<0><<<dim3(48, 32), 256, 0, stream>>>(xb, wqkvT, b_qkv, qbuf, kbuf, vtbuf, nullptr);
  k_attn<<<dim3(32, 32), 256, 0, stream>>>(qbuf, kbuf, vtbuf, ctxb);
  k_gemm<1><<<dim3(16, 32), 256, 0, stream>>>(ctxb, woT, nullptr, nullptr, nullptr, nullptr, outp);
}

// Round 5
// 425.107 us; speedup vs baseline: 1.4691x; 1.0970x over previous
//
#include <hip/hip_runtime.h>
#include <cstdint>
#include <cstddef>

typedef __attribute__((ext_vector_type(8))) short bf16x8;
typedef __attribute__((ext_vector_type(4))) float f32x4;
typedef __attribute__((ext_vector_type(4))) unsigned short ushort4_;

#define MFMA16(a, b, c) __builtin_amdgcn_mfma_f32_16x16x32_bf16((a), (b), (c), 0, 0, 0)

__device__ __forceinline__ unsigned short f2bf(float f) {
  union { float f; unsigned u; } c; c.f = f;
  unsigned r = c.u + 0x7fffu + ((c.u >> 16) & 1u);
  return (unsigned short)(r >> 16);
}

// async global->LDS, 16B per lane. LDS ptr must be wave-uniform; HW writes
// lane i at lds + i*16 (m97/m104). Swizzle goes into the SOURCE address.
__device__ __forceinline__ void gl_lds16(const unsigned short* g, unsigned short* l) {
  __builtin_amdgcn_global_load_lds(
      (const __attribute__((address_space(1))) void*)g,
      (__attribute__((address_space(3))) void*)l, 16, 0, 0);
}

// ---------------- fp32 -> bf16 ----------------
__global__ __launch_bounds__(256) void k_cvt(const float* __restrict__ x,
                                             unsigned short* __restrict__ y) {
  int i = blockIdx.x * 256 + threadIdx.x;
  float4 v = reinterpret_cast<const float4*>(x)[i];
  ushort4_ o;
  o.x = f2bf(v.x); o.y = f2bf(v.y); o.z = f2bf(v.z); o.w = f2bf(v.w);
  reinterpret_cast<ushort4_*>(y)[i] = o;
}

// ---------------- W[K=2048][N] fp32 -> WT[N][2048] bf16 ----------------
__global__ __launch_bounds__(256) void k_transpose_cvt(const float* __restrict__ W,
                                                       unsigned short* __restrict__ WT,
                                                       int N) {
  __shared__ unsigned short t[64][65];
  const int n0 = blockIdx.x * 64;
  const int k0 = blockIdx.y * 64;
  const int tid = threadIdx.x;
#pragma unroll
  for (int i = 0; i < 16; i++) {
    int li = tid + i * 256;
    int kk = li >> 6, nn = li & 63;
    t[kk][nn] = f2bf(W[(size_t)(k0 + kk) * N + (n0 + nn)]);
  }
  __syncthreads();
#pragma unroll
  for (int i = 0; i < 16; i++) {
    int li = tid + i * 256;
    int nn = li >> 6, kk = li & 63;
    WT[(size_t)(n0 + nn) * 2048 + (k0 + kk)] = t[kk][nn];
  }
}

// ---------------- GEMM: C[128x128]/block, A[M][2048] bf16, Bt[N][2048] bf16
template <int MODE>
__global__ __launch_bounds__(256) void k_gemm(const unsigned short* __restrict__ A,
                                              const unsigned short* __restrict__ Bt,
                                              const float* __restrict__ bias,
                                              unsigned short* __restrict__ qb,
                                              unsigned short* __restrict__ kb,
                                              unsigned short* __restrict__ vtb,
                                              float* __restrict__ outp) {
  __shared__ __align__(16) unsigned short As[128 * 64];
  __shared__ __align__(16) unsigned short Bs[128 * 64];
  const int tid = threadIdx.x;
  const int lane = tid & 63, wid = tid >> 6;
  const int quad = lane >> 4, l16 = lane & 15;
  const int wm = wid >> 1, wn = wid & 1;
  const int m0 = blockIdx.y * 128, n0 = blockIdx.x * 128;

  f32x4 acc[4][4];
#pragma unroll
  for (int i = 0; i < 4; i++)
#pragma unroll
    for (int j = 0; j < 4; j++) {
      f32x4 z = {0.f, 0.f, 0.f, 0.f};
      acc[i][j] = z;
    }

  for (int k0 = 0; k0 < 2048; k0 += 64) {
    __syncthreads();
#pragma unroll
    for (int i = 0; i < 4; i++) {
      int slotbase = wid * 64 + i * 256;
      int slot = slotbase + lane;
      int row = slot >> 3, chs = slot & 7, gch = chs ^ (row & 7);
      gl_lds16(A + (size_t)(m0 + row) * 2048 + k0 + gch * 8, &As[slotbase * 8]);
      gl_lds16(Bt + (size_t)(n0 + row) * 2048 + k0 + gch * 8, &Bs[slotbase * 8]);
    }
    __syncthreads();
#pragma unroll
    for (int kc = 0; kc < 2; kc++) {
      bf16x8 af[4], bfr[4];
#pragma unroll
      for (int mt = 0; mt < 4; mt++) {
        int r = wm * 64 + mt * 16 + l16;
        int ch = kc * 4 + quad;
        af[mt] = *reinterpret_cast<const bf16x8*>(&As[r * 64 + ((ch ^ (r & 7)) * 8)]);
      }
#pragma unroll
      for (int nt = 0; nt < 4; nt++) {
        int r = wn * 64 + nt * 16 + l16;
        int ch = kc * 4 + quad;
        bfr[nt] = *reinterpret_cast<const bf16x8*>(&Bs[r * 64 + ((ch ^ (r & 7)) * 8)]);
      }
#pragma unroll
      for (int mt = 0; mt < 4; mt++)
#pragma unroll
        for (int nt = 0; nt < 4; nt++)
          acc[mt][nt] = MFMA16(af[mt], bfr[nt], acc[mt][nt]);
    }
  }

  const int mbase = m0 + wm * 64;
  const int nbase = n0 + wn * 64;
  if (MODE == 0) {
#pragma unroll
    for (int nt = 0; nt < 4; nt++) {
      int n = nbase + nt * 16 + l16;
      float bv = bias[n];
      int seg = n >> 11;  // 0=q,1=k,2=v
      int h = (n >> 7) & 15;
      int d = n & 127;
#pragma unroll
      for (int mt = 0; mt < 4; mt++) {
        int mrow = mbase + mt * 16 + quad * 4;
        int b = mrow >> 11, s = mrow & 2047;
        if (seg == 2) {
          ushort4_ pk;
          pk.x = f2bf(acc[mt][nt][0] + bv);
          pk.y = f2bf(acc[mt][nt][1] + bv);
          pk.z = f2bf(acc[mt][nt][2] + bv);
          pk.w = f2bf(acc[mt][nt][3] + bv);
          *reinterpret_cast<ushort4_*>(vtb + ((size_t)(b * 16 + h) * 128 + d) * 2048 + s) = pk;
        } else {
          unsigned short* dst = (seg == 0 ? qb : kb);
          size_t base = (size_t)(b * 16 + h) * 2048;
#pragma unroll
          for (int rg = 0; rg < 4; rg++)
            dst[(base + (s + rg)) * 128 + d] = f2bf(acc[mt][nt][rg] + bv);
        }
      }
    }
  } else {
#pragma unroll
    for (int nt = 0; nt < 4; nt++) {
      int n = nbase + nt * 16 + l16;
#pragma unroll
      for (int mt = 0; mt < 4; mt++) {
        int mrow = mbase + mt * 16 + quad * 4;
#pragma unroll
        for (int rg = 0; rg < 4; rg++)
          outp[(size_t)(mrow + rg) * 2048 + n] = acc[mt][nt][rg];
      }
    }
  }
}

// ---------------- flash attention: 128 q-rows, 8 waves x 16 rows ----------------
// S^T = K·Q^T orientation, per-lane online softmax, O^T accumulation.
// KV tiles of 64, double-buffered, async global_load_lds prefetch across the
// barrier (vmcnt drain lands after a full compute phase).
// LDS: Ks 32K + Vs 32K + Ps 16K = 80KB -> 2 blocks/CU = 16 waves/CU.
__global__ __launch_bounds__(512) void k_attn(const unsigned short* __restrict__ qb,
                                              const unsigned short* __restrict__ kb,
                                              const unsigned short* __restrict__ vtb,
                                              unsigned short* __restrict__ ctx) {
  __shared__ __align__(16) unsigned short Ks[2][64 * 128];  // [buf][key][dim]
  __shared__ __align__(16) unsigned short Vs[2][128 * 64];  // [buf][dim][key]
  __shared__ __align__(16) unsigned short Ps[128 * 64];     // [q][key]
  const int qt = (gridDim.x - 1) - blockIdx.x;
  const int bh = blockIdx.y;
  const int tid = threadIdx.x;
  const int lane = tid & 63, w = tid >> 6;   // w in 0..7
  const int quad = lane >> 4, l16 = lane & 15;
  const int qbase = qt * 128;
  const unsigned short* Qh = qb + (size_t)bh * 2048 * 128;
  const unsigned short* Kh = kb + (size_t)bh * 2048 * 128;
  const unsigned short* Vh = vtb + (size_t)bh * 128 * 2048;

  const int q_lo = qbase + w * 16;  // this wave's 16 q rows: q_lo + l16
  const int nkv = 2 * qt + 2;
  const float sl2 = 0.12751741f;  // (1/sqrt(128)) * log2(e)

  // Q fragments (B-operand layout: n=q at l16, k=d at kc*32+quad*8)
  bf16x8 qf[4];
#pragma unroll
  for (int kc = 0; kc < 4; kc++)
    qf[kc] = *reinterpret_cast<const bf16x8*>(
        Qh + (size_t)(q_lo + l16) * 128 + kc * 32 + quad * 8);

  // O^T accumulator: 8 d-tiles of 16, rows=d (quad*4+rg), cols=q (l16)
  f32x4 o[8];
#pragma unroll
  for (int dt = 0; dt < 8; dt++) {
    f32x4 z = {0.f, 0.f, 0.f, 0.f};
    o[dt] = z;
  }
  float m_run = -1e30f, l_run = 0.f;

  auto stage = [&](int kvb, int bsel) {
    unsigned short* Kd = &Ks[bsel][0];
    unsigned short* Vd = &Vs[bsel][0];
#pragma unroll
    for (int i = 0; i < 2; i++) {
      int slotbase = i * 512 + w * 64;  // wave-uniform
      int slot = slotbase + lane;
      int rowk = slot >> 4, chk = (slot & 15) ^ (rowk & 7);
      gl_lds16(Kh + (size_t)(kvb + rowk) * 128 + chk * 8, Kd + slotbase * 8);
      int rowv = slot >> 3, chv = (slot & 7) ^ (rowv & 7);
      gl_lds16(Vh + (size_t)rowv * 2048 + kvb + chv * 8, Vd + slotbase * 8);
    }
  };

  stage(0, 0);

  for (int kv = 0; kv < nkv; kv++) {
    const int kvb = kv * 64;
    const int cur = kv & 1;
    // own writes of buf[cur] (issued last iteration) must be complete; then
    // block-wide barrier. Prefetch of buf[cur^1] stays in flight across it.
    asm volatile("s_waitcnt vmcnt(0)" ::: "memory");
    asm volatile("s_barrier" ::: "memory");
    if (kv + 1 < nkv) stage(kvb + 64, cur ^ 1);
    if (kvb > q_lo + 15) continue;  // fully masked for this wave

    const unsigned short* Kc = &Ks[cur][0];
    const unsigned short* Vc = &Vs[cur][0];

    // S^T = K Q^T : rows=keys (quad*4+rg per nt tile), cols=q (l16)
    f32x4 sacc[4];
#pragma unroll
    for (int nt = 0; nt < 4; nt++) {
      f32x4 z = {0.f, 0.f, 0.f, 0.f};
      sacc[nt] = z;
    }
#pragma unroll
    for (int kc = 0; kc < 4; kc++) {
      bf16x8 kf[4];
#pragma unroll
      for (int nt = 0; nt < 4; nt++) {
        int r = nt * 16 + l16, ch = kc * 4 + quad;
        kf[nt] = *reinterpret_cast<const bf16x8*>(&Kc[r * 128 + ((ch ^ (r & 7)) * 8)]);
      }
#pragma unroll
      for (int nt = 0; nt < 4; nt++)
        sacc[nt] = MFMA16(kf[nt], qf[kc], sacc[nt]);
    }

    // online softmax: per-lane over 16 in-register keys + 2 shfl rounds
    const bool needmask = (kvb + 63) > q_lo;
    const int qabs = q_lo + l16;
    float tmax = -1e30f;
#pragma unroll
    for (int nt = 0; nt < 4; nt++)
#pragma unroll
      for (int rg = 0; rg < 4; rg++) {
        float v = sacc[nt][rg] * sl2;
        if (needmask && (kvb + nt * 16 + quad * 4 + rg) > qabs) v = -1e30f;
        sacc[nt][rg] = v;
        tmax = fmaxf(tmax, v);
      }
    tmax = fmaxf(tmax, __shfl_xor(tmax, 16));
    tmax = fmaxf(tmax, __shfl_xor(tmax, 32));
    float mnew = fmaxf(m_run, tmax);
    float alpha = exp2f(m_run - mnew);
    m_run = mnew;
    float rsum = 0.f;
#pragma unroll
    for (int nt = 0; nt < 4; nt++)
#pragma unroll
      for (int rg = 0; rg < 4; rg++) {
        float p = exp2f(sacc[nt][rg] - mnew);
        sacc[nt][rg] = p;
        rsum += p;
      }
    rsum += __shfl_xor(rsum, 16);
    rsum += __shfl_xor(rsum, 32);
    l_run = l_run * alpha + rsum;
#pragma unroll
    for (int dt = 0; dt < 8; dt++)
#pragma unroll
      for (int rg = 0; rg < 4; rg++) o[dt][rg] *= alpha;

    // P^T (rows=keys, cols=q) -> Ps[q][key], per-wave rows w*16+l16,
    // vectorized 8B stores, 16B-chunk swizzle (row&7 == l16&7 since w*16%16==0)
#pragma unroll
    for (int nt = 0; nt < 4; nt++) {
      ushort4_ pk;
      pk.x = f2bf(sacc[nt][0]);
      pk.y = f2bf(sacc[nt][1]);
      pk.z = f2bf(sacc[nt][2]);
      pk.w = f2bf(sacc[nt][3]);
      int chunk = nt * 2 + (quad >> 1);
      *reinterpret_cast<ushort4_*>(
          &Ps[(w * 16 + l16) * 64 + ((chunk ^ (l16 & 7)) * 8) + (quad & 1) * 4]) = pk;
    }
    asm volatile("s_waitcnt lgkmcnt(0)" ::: "memory");  // same-wave rows only

    // O^T += V^T · P^T : A=V^T frag (m=d), B=P^T frag (n=q, k=key)
#pragma unroll
    for (int kc = 0; kc < 2; kc++) {
      int chunkr = kc * 4 + quad;
      bf16x8 pf = *reinterpret_cast<const bf16x8*>(
          &Ps[(w * 16 + l16) * 64 + ((chunkr ^ (l16 & 7)) * 8)]);
#pragma unroll
      for (int dt = 0; dt < 8; dt++) {
        int r = dt * 16 + l16, ch = kc * 4 + quad;
        bf16x8 vf = *reinterpret_cast<const bf16x8*>(&Vc[r * 64 + ((ch ^ (r & 7)) * 8)]);
        o[dt] = MFMA16(vf, pf, o[dt]);
      }
    }
  }

  const int b = bh >> 4, h = bh & 15;
  const float inv = 1.f / l_run;
  const int s = q_lo + l16;
#pragma unroll
  for (int dt = 0; dt < 8; dt++) {
    int d0 = dt * 16 + quad * 4;
    ushort4_ pk;
    pk.x = f2bf(o[dt][0] * inv);
    pk.y = f2bf(o[dt][1] * inv);
    pk.z = f2bf(o[dt][2] * inv);
    pk.w = f2bf(o[dt][3] * inv);
    *reinterpret_cast<ushort4_*>(
        &ctx[((size_t)b * 2048 + s) * 2048 + h * 128 + d0]) = pk;
  }
}

extern "C" void kernel_launch(void* const* d_in, const int* in_sizes, int n_in,
                              void* d_out, int out_size, void* d_ws, size_t ws_size,
                              hipStream_t stream) {
  const float* x = (const float*)d_in[0];
  const float* w_qkv = (const float*)d_in[1];
  const float* b_qkv = (const float*)d_in[2];
  const float* w_o = (const float*)d_in[3];
  float* outp = (float*)d_out;

  unsigned short* ws = (unsigned short*)d_ws;
  unsigned short* xb    = ws;
  unsigned short* wqkvT = xb + 8388608;
  unsigned short* woT   = wqkvT + 12582912;
  unsigned short* qbuf  = woT + 4194304;
  unsigned short* kbuf  = qbuf + 8388608;
  unsigned short* vtbuf = kbuf + 8388608;
  unsigned short* ctxb  = vtbuf + 8388608;
  // total ~117.4 MB

  k_cvt<<<8192, 256, 0, stream>>>(x, xb);
  k_transpose_cvt<<<dim3(96, 32), 256, 0, stream>>>(w_qkv, wqkvT, 6144);
  k_transpose_cvt<<<dim3(32, 32), 256, 0, stream>>>(w_o, woT, 2048);
  k_gemm<0><<<dim3(48, 32), 256, 0, stream>>>(xb, wqkvT, b_qkv, qbuf, kbuf, vtbuf, nullptr);
  k_attn<<<dim3(16, 32), 512, 0, stream>>>(qbuf, kbuf, vtbuf, ctxb);
  k_gemm<1><<<dim3(16, 32), 256, 0, stream>>>(ctxb, woT, nullptr, nullptr, nullptr, nullptr, outp);
}

// Round 6
// 422.494 us; speedup vs baseline: 1.4782x; 1.0062x over previous
//
#include <hip/hip_runtime.h>
#include <cstdint>
#include <cstddef>

typedef __attribute__((ext_vector_type(8))) short bf16x8;
typedef __attribute__((ext_vector_type(4))) float f32x4;
typedef __attribute__((ext_vector_type(4))) unsigned short ushort4_;

#define MFMA16(a, b, c) __builtin_amdgcn_mfma_f32_16x16x32_bf16((a), (b), (c), 0, 0, 0)

__device__ __forceinline__ unsigned short f2bf(float f) {
  union { float f; unsigned u; } c; c.f = f;
  unsigned r = c.u + 0x7fffu + ((c.u >> 16) & 1u);
  return (unsigned short)(r >> 16);
}

// async global->LDS, 16B per lane. LDS ptr must be wave-uniform; HW writes
// lane i at lds + i*16 (m97/m104). Swizzle goes into the SOURCE address.
__device__ __forceinline__ void gl_lds16(const unsigned short* g, unsigned short* l) {
  __builtin_amdgcn_global_load_lds(
      (const __attribute__((address_space(1))) void*)g,
      (__attribute__((address_space(3))) void*)l, 16, 0, 0);
}

// ---------------- fused prep: x->bf16 cvt + both weight transposes ----------------
// blocks [0,8192): cvt; [8192,11264): w_qkv^T (96x32); [11264,12288): w_o^T (32x32)
__global__ __launch_bounds__(256) void k_prep(const float* __restrict__ x,
                                              unsigned short* __restrict__ xb,
                                              const float* __restrict__ wqkv,
                                              unsigned short* __restrict__ wqkvT,
                                              const float* __restrict__ wo,
                                              unsigned short* __restrict__ woT) {
  __shared__ unsigned short t[64][65];
  const int blk = blockIdx.x;
  const int tid = threadIdx.x;
  if (blk < 8192) {
    int i = blk * 256 + tid;
    float4 v = reinterpret_cast<const float4*>(x)[i];
    ushort4_ o;
    o.x = f2bf(v.x); o.y = f2bf(v.y); o.z = f2bf(v.z); o.w = f2bf(v.w);
    reinterpret_cast<ushort4_*>(xb)[i] = o;
    return;
  }
  const float* W;
  unsigned short* WT;
  int n0, k0, N;
  if (blk < 11264) {
    int local = blk - 8192;
    W = wqkv; WT = wqkvT; N = 6144;
    n0 = (local % 96) * 64; k0 = (local / 96) * 64;
  } else {
    int local = blk - 11264;
    W = wo; WT = woT; N = 2048;
    n0 = (local % 32) * 64; k0 = (local / 32) * 64;
  }
#pragma unroll
  for (int i = 0; i < 16; i++) {
    int li = tid + i * 256;
    int kk = li >> 6, nn = li & 63;
    t[kk][nn] = f2bf(W[(size_t)(k0 + kk) * N + (n0 + nn)]);
  }
  __syncthreads();
#pragma unroll
  for (int i = 0; i < 16; i++) {
    int li = tid + i * 256;
    int nn = li >> 6, kk = li & 63;
    WT[(size_t)(n0 + nn) * 2048 + (k0 + kk)] = t[kk][nn];
  }
}

// ---------------- GEMM: C[128x128]/block, A[M][2048] bf16, Bt[N][2048] bf16
template <int MODE>
__global__ __launch_bounds__(256) void k_gemm(const unsigned short* __restrict__ A,
                                              const unsigned short* __restrict__ Bt,
                                              const float* __restrict__ bias,
                                              unsigned short* __restrict__ qb,
                                              unsigned short* __restrict__ kb,
                                              unsigned short* __restrict__ vtb,
                                              float* __restrict__ outp) {
  __shared__ __align__(16) unsigned short As[128 * 64];
  __shared__ __align__(16) unsigned short Bs[128 * 64];
  const int tid = threadIdx.x;
  const int lane = tid & 63, wid = tid >> 6;
  const int quad = lane >> 4, l16 = lane & 15;
  const int wm = wid >> 1, wn = wid & 1;
  const int m0 = blockIdx.y * 128, n0 = blockIdx.x * 128;

  f32x4 acc[4][4];
#pragma unroll
  for (int i = 0; i < 4; i++)
#pragma unroll
    for (int j = 0; j < 4; j++) {
      f32x4 z = {0.f, 0.f, 0.f, 0.f};
      acc[i][j] = z;
    }

  for (int k0 = 0; k0 < 2048; k0 += 64) {
    __syncthreads();
#pragma unroll
    for (int i = 0; i < 4; i++) {
      int slotbase = wid * 64 + i * 256;
      int slot = slotbase + lane;
      int row = slot >> 3, chs = slot & 7, gch = chs ^ (row & 7);
      gl_lds16(A + (size_t)(m0 + row) * 2048 + k0 + gch * 8, &As[slotbase * 8]);
      gl_lds16(Bt + (size_t)(n0 + row) * 2048 + k0 + gch * 8, &Bs[slotbase * 8]);
    }
    __syncthreads();
#pragma unroll
    for (int kc = 0; kc < 2; kc++) {
      bf16x8 af[4], bfr[4];
#pragma unroll
      for (int mt = 0; mt < 4; mt++) {
        int r = wm * 64 + mt * 16 + l16;
        int ch = kc * 4 + quad;
        af[mt] = *reinterpret_cast<const bf16x8*>(&As[r * 64 + ((ch ^ (r & 7)) * 8)]);
      }
#pragma unroll
      for (int nt = 0; nt < 4; nt++) {
        int r = wn * 64 + nt * 16 + l16;
        int ch = kc * 4 + quad;
        bfr[nt] = *reinterpret_cast<const bf16x8*>(&Bs[r * 64 + ((ch ^ (r & 7)) * 8)]);
      }
#pragma unroll
      for (int mt = 0; mt < 4; mt++)
#pragma unroll
        for (int nt = 0; nt < 4; nt++)
          acc[mt][nt] = MFMA16(af[mt], bfr[nt], acc[mt][nt]);
    }
  }

  const int mbase = m0 + wm * 64;
  const int nbase = n0 + wn * 64;
  if (MODE == 0) {
#pragma unroll
    for (int nt = 0; nt < 4; nt++) {
      int n = nbase + nt * 16 + l16;
      float bv = bias[n];
      int seg = n >> 11;  // 0=q,1=k,2=v
      int h = (n >> 7) & 15;
      int d = n & 127;
#pragma unroll
      for (int mt = 0; mt < 4; mt++) {
        int mrow = mbase + mt * 16 + quad * 4;
        int b = mrow >> 11, s = mrow & 2047;
        if (seg == 2) {
          ushort4_ pk;
          pk.x = f2bf(acc[mt][nt][0] + bv);
          pk.y = f2bf(acc[mt][nt][1] + bv);
          pk.z = f2bf(acc[mt][nt][2] + bv);
          pk.w = f2bf(acc[mt][nt][3] + bv);
          *reinterpret_cast<ushort4_*>(vtb + ((size_t)(b * 16 + h) * 128 + d) * 2048 + s) = pk;
        } else {
          unsigned short* dst = (seg == 0 ? qb : kb);
          size_t base = (size_t)(b * 16 + h) * 2048;
#pragma unroll
          for (int rg = 0; rg < 4; rg++)
            dst[(base + (s + rg)) * 128 + d] = f2bf(acc[mt][nt][rg] + bv);
        }
      }
    }
  } else {
#pragma unroll
    for (int nt = 0; nt < 4; nt++) {
      int n = nbase + nt * 16 + l16;
#pragma unroll
      for (int mt = 0; mt < 4; mt++) {
        int mrow = mbase + mt * 16 + quad * 4;
#pragma unroll
        for (int rg = 0; rg < 4; rg++)
          outp[(size_t)(mrow + rg) * 2048 + n] = acc[mt][nt][rg];
      }
    }
  }
}

// ---------------- flash attention: 128 q-rows, 4 waves x 32 rows ----------------
// S^T = K·Q^T orientation, per-lane online softmax, O^T accumulation.
// 32 q/wave (two 16-q halves): kf/vf LDS reads amortize over 2x outputs.
// KV tiles of 64, double-buffered, async prefetch across the barrier.
// LDS: Ks 32K + Vs 32K + Ps 16K = 80KB -> 2 blocks/CU = 8 waves/CU.
__global__ __launch_bounds__(256, 2) void k_attn(const unsigned short* __restrict__ qb,
                                                 const unsigned short* __restrict__ kb,
                                                 const unsigned short* __restrict__ vtb,
                                                 unsigned short* __restrict__ ctx) {
  __shared__ __align__(16) unsigned short Ks[2][64 * 128];  // [buf][key][dim]
  __shared__ __align__(16) unsigned short Vs[2][128 * 64];  // [buf][dim][key]
  __shared__ __align__(16) unsigned short Ps[128 * 64];     // [q][key]
  const int qt = (gridDim.x - 1) - blockIdx.x;  // longest first
  const int bh = blockIdx.y;
  const int tid = threadIdx.x;
  const int lane = tid & 63, w = tid >> 6;   // w in 0..3
  const int quad = lane >> 4, l16 = lane & 15;
  const int qbase = qt * 128;
  const unsigned short* Qh = qb + (size_t)bh * 2048 * 128;
  const unsigned short* Kh = kb + (size_t)bh * 2048 * 128;
  const unsigned short* Vh = vtb + (size_t)bh * 128 * 2048;

  const int q_lo = qbase + w * 32;  // wave rows: q_lo + half*16 + l16
  const int nkv = 2 * qt + 2;
  const float sl2 = 0.12751741f;  // (1/sqrt(128)) * log2(e)

  // Q fragments (B-operand layout: n=q at l16, k=d at kc*32+quad*8), 2 halves
  bf16x8 qf[2][4];
#pragma unroll
  for (int half = 0; half < 2; half++)
#pragma unroll
    for (int kc = 0; kc < 4; kc++)
      qf[half][kc] = *reinterpret_cast<const bf16x8*>(
          Qh + (size_t)(q_lo + half * 16 + l16) * 128 + kc * 32 + quad * 8);

  // O^T accumulator per half: rows=d (quad*4+rg), cols=q (l16)
  f32x4 o[2][8];
#pragma unroll
  for (int half = 0; half < 2; half++)
#pragma unroll
    for (int dt = 0; dt < 8; dt++) {
      f32x4 z = {0.f, 0.f, 0.f, 0.f};
      o[half][dt] = z;
    }
  float m_run[2] = {-1e30f, -1e30f}, l_run[2] = {0.f, 0.f};

  auto stage = [&](int kvb, int bsel) {
    unsigned short* Kd = &Ks[bsel][0];
    unsigned short* Vd = &Vs[bsel][0];
#pragma unroll
    for (int i = 0; i < 4; i++) {
      int slotbase = i * 256 + w * 64;  // wave-uniform
      int slot = slotbase + lane;
      int rowk = slot >> 4, chk = (slot & 15) ^ (rowk & 7);
      gl_lds16(Kh + (size_t)(kvb + rowk) * 128 + chk * 8, Kd + slotbase * 8);
      int rowv = slot >> 3, chv = (slot & 7) ^ (rowv & 7);
      gl_lds16(Vh + (size_t)rowv * 2048 + kvb + chv * 8, Vd + slotbase * 8);
    }
  };

  stage(0, 0);

  for (int kv = 0; kv < nkv; kv++) {
    const int kvb = kv * 64;
    const int cur = kv & 1;
    // own writes of buf[cur] (issued last iteration) complete; prefetch of
    // buf[cur^1] stays in flight across the barrier.
    asm volatile("s_waitcnt vmcnt(0)" ::: "memory");
    asm volatile("s_barrier" ::: "memory");
    if (kv + 1 < nkv) stage(kvb + 64, cur ^ 1);
    if (kvb > q_lo + 31) continue;  // fully masked for this wave

    const unsigned short* Kc = &Ks[cur][0];
    const unsigned short* Vc = &Vs[cur][0];

    // S^T = K Q^T, both halves share kf reads
    f32x4 sacc[2][4];
#pragma unroll
    for (int half = 0; half < 2; half++)
#pragma unroll
      for (int nt = 0; nt < 4; nt++) {
        f32x4 z = {0.f, 0.f, 0.f, 0.f};
        sacc[half][nt] = z;
      }
#pragma unroll
    for (int kc = 0; kc < 4; kc++) {
#pragma unroll
      for (int nt = 0; nt < 4; nt++) {
        int r = nt * 16 + l16, ch = kc * 4 + quad;
        bf16x8 kf = *reinterpret_cast<const bf16x8*>(&Kc[r * 128 + ((ch ^ (r & 7)) * 8)]);
        sacc[0][nt] = MFMA16(kf, qf[0][kc], sacc[0][nt]);
        sacc[1][nt] = MFMA16(kf, qf[1][kc], sacc[1][nt]);
      }
    }

    // online softmax per half: per-lane over 16 in-register keys + 2 shfl rounds
    const bool needmask = (kvb + 63) > q_lo;
#pragma unroll
    for (int half = 0; half < 2; half++) {
      const int qabs = q_lo + half * 16 + l16;
      float tmax = -1e30f;
#pragma unroll
      for (int nt = 0; nt < 4; nt++)
#pragma unroll
        for (int rg = 0; rg < 4; rg++) {
          float v = sacc[half][nt][rg] * sl2;
          if (needmask && (kvb + nt * 16 + quad * 4 + rg) > qabs) v = -1e30f;
          sacc[half][nt][rg] = v;
          tmax = fmaxf(tmax, v);
        }
      tmax = fmaxf(tmax, __shfl_xor(tmax, 16));
      tmax = fmaxf(tmax, __shfl_xor(tmax, 32));
      float mnew = fmaxf(m_run[half], tmax);
      float alpha = exp2f(m_run[half] - mnew);
      m_run[half] = mnew;
      float rsum = 0.f;
#pragma unroll
      for (int nt = 0; nt < 4; nt++)
#pragma unroll
        for (int rg = 0; rg < 4; rg++) {
          float p = exp2f(sacc[half][nt][rg] - mnew);
          sacc[half][nt][rg] = p;
          rsum += p;
        }
      rsum += __shfl_xor(rsum, 16);
      rsum += __shfl_xor(rsum, 32);
      l_run[half] = l_run[half] * alpha + rsum;
#pragma unroll
      for (int dt = 0; dt < 8; dt++)
#pragma unroll
        for (int rg = 0; rg < 4; rg++) o[half][dt][rg] *= alpha;

      // P^T -> Ps[q][key], per-wave rows, 8B vector stores, 16B-chunk swizzle
#pragma unroll
      for (int nt = 0; nt < 4; nt++) {
        ushort4_ pk;
        pk.x = f2bf(sacc[half][nt][0]);
        pk.y = f2bf(sacc[half][nt][1]);
        pk.z = f2bf(sacc[half][nt][2]);
        pk.w = f2bf(sacc[half][nt][3]);
        int chunk = nt * 2 + (quad >> 1);
        *reinterpret_cast<ushort4_*>(
            &Ps[(w * 32 + half * 16 + l16) * 64 + ((chunk ^ (l16 & 7)) * 8) +
                (quad & 1) * 4]) = pk;
      }
    }
    asm volatile("s_waitcnt lgkmcnt(0)" ::: "memory");  // same-wave rows only

    // O^T += V^T · P^T, both halves share vf reads
#pragma unroll
    for (int kc = 0; kc < 2; kc++) {
      int chunkr = kc * 4 + quad;
      bf16x8 pf0 = *reinterpret_cast<const bf16x8*>(
          &Ps[(w * 32 + l16) * 64 + ((chunkr ^ (l16 & 7)) * 8)]);
      bf16x8 pf1 = *reinterpret_cast<const bf16x8*>(
          &Ps[(w * 32 + 16 + l16) * 64 + ((chunkr ^ (l16 & 7)) * 8)]);
#pragma unroll
      for (int dt = 0; dt < 8; dt++) {
        int r = dt * 16 + l16, ch = kc * 4 + quad;
        bf16x8 vf = *reinterpret_cast<const bf16x8*>(&Vc[r * 64 + ((ch ^ (r & 7)) * 8)]);
        o[0][dt] = MFMA16(vf, pf0, o[0][dt]);
        o[1][dt] = MFMA16(vf, pf1, o[1][dt]);
      }
    }
  }

  const int b = bh >> 4, h = bh & 15;
#pragma unroll
  for (int half = 0; half < 2; half++) {
    const float inv = 1.f / l_run[half];
    const int s = q_lo + half * 16 + l16;
#pragma unroll
    for (int dt = 0; dt < 8; dt++) {
      int d0 = dt * 16 + quad * 4;
      ushort4_ pk;
      pk.x = f2bf(o[half][dt][0] * inv);
      pk.y = f2bf(o[half][dt][1] * inv);
      pk.z = f2bf(o[half][dt][2] * inv);
      pk.w = f2bf(o[half][dt][3] * inv);
      *reinterpret_cast<ushort4_*>(
          &ctx[((size_t)b * 2048 + s) * 2048 + h * 128 + d0]) = pk;
    }
  }
}

extern "C" void kernel_launch(void* const* d_in, const int* in_sizes, int n_in,
                              void* d_out, int out_size, void* d_ws, size_t ws_size,
                              hipStream_t stream) {
  const float* x = (const float*)d_in[0];
  const float* w_qkv = (const float*)d_in[1];
  const float* b_qkv = (const float*)d_in[2];
  const float* w_o = (const float*)d_in[3];
  float* outp = (float*)d_out;

  unsigned short* ws = (unsigned short*)d_ws;
  unsigned short* xb    = ws;
  unsigned short* wqkvT = xb + 8388608;
  unsigned short* woT   = wqkvT + 12582912;
  unsigned short* qbuf  = woT + 4194304;
  unsigned short* kbuf  = qbuf + 8388608;
  unsigned short* vtbuf = kbuf + 8388608;
  unsigned short* ctxb  = vtbuf + 8388608;
  // total ~117.4 MB

  k_prep<<<12288, 256, 0, stream>>>(x, xb, w_qkv, wqkvT, w_o, woT);
  k_gemm<0><<<dim3(48, 32), 256, 0, stream>>>(xb, wqkvT, b_qkv, qbuf, kbuf, vtbuf, nullptr);
  k_attn<<<dim3(16, 32), 256, 0, stream>>>(qbuf, kbuf, vtbuf, ctxb);
  k_gemm<1><<<dim3(16, 32), 256, 0, stream>>>(ctxb, woT, nullptr, nullptr, nullptr, nullptr, outp);
}